// Round 5
// baseline (52.232 us; speedup 1.0000x reference)
//
#include <hip/hip_runtime.h>

// B=32, R=3136 (=56*56), O=20, D=32. Memory-bound: ~294 MB irreducible.
// R1 structure, BLOCK 512->1024: full 128B result-store lines per block.
#define NB 32
#define NR 3136
#define NO 20
#define ND 32
#define RPB 32            // rays per block (one ray per 32-lane half-wave)
#define BLOCK (RPB * 32)  // 1024

typedef float f4v __attribute__((ext_vector_type(4)));

__global__ __launch_bounds__(BLOCK) void ray_composite(
    const float* __restrict__ form,    // [B,R,O,D]
    const float* __restrict__ depth,   // [B,R,O]
    const float* __restrict__ trans,   // [B,R,O]
    float* __restrict__ out_res,       // [B,D,H,W]
    float* __restrict__ out_pond)      // [B,R,O]
{
  __shared__ float res_lds[RPB][36];     // pad 32->36: float4-aligned
  __shared__ float pond_lds[RPB * NO];

  const int t    = threadIdx.x;
  const int rib  = t >> 5;               // 0..31
  const int lane = t & 31;
  const int ray0 = blockIdx.x * RPB;
  const int ray  = ray0 + rib;
  const int b    = ray0 / NR;            // RPB | NR: no batch straddle
  const int r0   = ray0 - b * NR;

  // ---- phase 1: ponderation (lane o<20 owns object o of its ray) ----
  float d_o = 0.f, t_o = 0.f;
  if (lane < NO) {
    d_o = depth[(size_t)ray * NO + lane];
    t_o = trans[(size_t)ray * NO + lane];
  }
  float acc = 0.f;
#pragma unroll
  for (int j = 0; j < NO; ++j) {
    const float dj = __shfl(d_o, j, 32);
    const float tj = __shfl(t_o, j, 32);
    const float s  = 1.f / (1.f + __expf(-1000.f * (d_o - dj)));
    if (j != lane) acc += tj * s;
  }
  float pond = __expf(acc) * (1.f - __expf(t_o));
  if (lane >= NO) pond = 0.f;
  if (lane < NO) pond_lds[rib * NO + lane] = pond;

  // ---- phase 2: res[d] = sum_o pond[o]*form[o][d], float4 loads ----
  const int c  = lane & 7;
  const int og = lane >> 3;
  const float* fbase = form + (size_t)ray * (NO * ND);
  f4v accv = {0.f, 0.f, 0.f, 0.f};
#pragma unroll
  for (int k = 0; k < 5; ++k) {
    const int o = og + 4 * k;
    const float p = __shfl(pond, o, 32);
    const f4v v = *reinterpret_cast<const f4v*>(fbase + o * ND + c * 4);
    accv += p * v;
  }
#pragma unroll
  for (int m = 8; m <= 16; m <<= 1) {   // reduce across the 4 row-groups
    accv.x += __shfl_xor(accv.x, m, 32);
    accv.y += __shfl_xor(accv.y, m, 32);
    accv.z += __shfl_xor(accv.z, m, 32);
    accv.w += __shfl_xor(accv.w, m, 32);
  }
  if (lane < 8)
    *reinterpret_cast<f4v*>(&res_lds[rib][lane * 4]) = accv;

  __syncthreads();

  // ---- phase 3: full-line coalesced stores ----
  // result: per d, 32 consecutive floats = one 128B line per block
  {
    const int d  = t >> 5;
    const int rr = t & 31;
    out_res[(size_t)b * (ND * NR) + (size_t)d * NR + r0 + rr] = res_lds[rr][d];
  }
  // ponderation: one contiguous 2560B run per block
  if (t < RPB * NO)
    out_pond[(size_t)ray0 * NO + t] = pond_lds[t];
}

extern "C" void kernel_launch(void* const* d_in, const int* in_sizes, int n_in,
                              void* d_out, int out_size, void* d_ws, size_t ws_size,
                              hipStream_t stream) {
  const float* form  = (const float*)d_in[0];
  const float* depth = (const float*)d_in[1];
  const float* trans = (const float*)d_in[2];

  float* out_res  = (float*)d_out;
  float* out_pond = out_res + (size_t)NB * ND * NR;

  dim3 grid((NB * NR) / RPB);   // 3136
  dim3 block(BLOCK);            // 1024
  ray_composite<<<grid, block, 0, stream>>>(form, depth, trans, out_res, out_pond);
}

// Round 6
// 51.112 us; speedup vs baseline: 1.0219x; 1.0219x over previous
//
#include <hip/hip_runtime.h>

// B=32, R=3136 (=56*56), O=20, D=32. Memory-bound: ~294 MB irreducible traffic.
// Best structure (R1, 50.1 us = 93% of 6.29 TB/s measured copy ceiling):
// 512-thread blocks, 1 ray per 32-lane half-wave, float4 form loads,
// LDS-transposed coalesced stores. R2 (2 rays/half-wave), R3 (nontemporal),
// R4 (1024-thread blocks) all regressed.
#define NB 32
#define NR 3136
#define NO 20
#define ND 32
#define RPB 16            // rays per block
#define BLOCK (RPB * 32)  // 512

typedef float f4v __attribute__((ext_vector_type(4)));

__global__ __launch_bounds__(BLOCK) void ray_composite(
    const float* __restrict__ form,    // [B,R,O,D]
    const float* __restrict__ depth,   // [B,R,O]
    const float* __restrict__ trans,   // [B,R,O]
    float* __restrict__ out_res,       // [B,D,H,W]
    float* __restrict__ out_pond)      // [B,R,O]
{
  __shared__ float res_lds[RPB][36];     // pad 32->36: float4-aligned, 2-way max
  __shared__ float pond_lds[RPB * NO];

  const int t    = threadIdx.x;
  const int rib  = t >> 5;
  const int lane = t & 31;
  const int ray0 = blockIdx.x * RPB;
  const int ray  = ray0 + rib;
  const int b    = ray0 / NR;            // RPB | NR: no batch straddle
  const int r0   = ray0 - b * NR;

  // ---- phase 1: ponderation (lane o<20 owns object o of its ray) ----
  float d_o = 0.f, t_o = 0.f;
  if (lane < NO) {
    d_o = depth[(size_t)ray * NO + lane];
    t_o = trans[(size_t)ray * NO + lane];
  }
  float acc = 0.f;
#pragma unroll
  for (int j = 0; j < NO; ++j) {
    const float dj = __shfl(d_o, j, 32);
    const float tj = __shfl(t_o, j, 32);
    const float s  = 1.f / (1.f + __expf(-1000.f * (d_o - dj)));
    if (j != lane) acc += tj * s;
  }
  float pond = __expf(acc) * (1.f - __expf(t_o));
  if (lane >= NO) pond = 0.f;
  if (lane < NO) pond_lds[rib * NO + lane] = pond;

  // ---- phase 2: res[d] = sum_o pond[o]*form[o][d], float4 loads ----
  // lane = og*8 + c: chunk c holds channels 4c..4c+3; row-group og covers
  // objects {og, og+4, ..., og+16}. Half-wave reads contiguous 512B.
  const int c  = lane & 7;
  const int og = lane >> 3;
  const float* fbase = form + (size_t)ray * (NO * ND);
  f4v accv = {0.f, 0.f, 0.f, 0.f};
#pragma unroll
  for (int k = 0; k < 5; ++k) {
    const int o = og + 4 * k;
    const float p = __shfl(pond, o, 32);
    const f4v v = *reinterpret_cast<const f4v*>(fbase + o * ND + c * 4);
    accv += p * v;
  }
#pragma unroll
  for (int m = 8; m <= 16; m <<= 1) {   // reduce across the 4 row-groups
    accv.x += __shfl_xor(accv.x, m, 32);
    accv.y += __shfl_xor(accv.y, m, 32);
    accv.z += __shfl_xor(accv.z, m, 32);
    accv.w += __shfl_xor(accv.w, m, 32);
  }
  if (lane < 8)
    *reinterpret_cast<f4v*>(&res_lds[rib][lane * 4]) = accv;

  __syncthreads();

  // ---- phase 3: coalesced stores ----
  // result: per d, 16 consecutive floats (64B segment per block)
  {
    const int d  = t >> 4;
    const int rr = t & 15;
    out_res[(size_t)b * (ND * NR) + (size_t)d * NR + r0 + rr] = res_lds[rr][d];
  }
  // ponderation: one contiguous 1280B run per block
  if (t < RPB * NO)
    out_pond[(size_t)ray0 * NO + t] = pond_lds[t];
}

extern "C" void kernel_launch(void* const* d_in, const int* in_sizes, int n_in,
                              void* d_out, int out_size, void* d_ws, size_t ws_size,
                              hipStream_t stream) {
  const float* form  = (const float*)d_in[0];
  const float* depth = (const float*)d_in[1];
  const float* trans = (const float*)d_in[2];

  float* out_res  = (float*)d_out;
  float* out_pond = out_res + (size_t)NB * ND * NR;

  dim3 grid((NB * NR) / RPB);   // 6272
  dim3 block(BLOCK);            // 512
  ray_composite<<<grid, block, 0, stream>>>(form, depth, trans, out_res, out_pond);
}